// Round 5
// baseline (429.757 us; speedup 1.0000x reference)
//
#include <hip/hip_runtime.h>

#define N_NODES 50000
#define N_EDGES 800000
#define DIM 128
#define N_LAYERS 3

typedef __attribute__((ext_vector_type(8))) short bf16x8;
typedef __attribute__((ext_vector_type(4))) float f32x4;

__device__ __forceinline__ unsigned short f2bf(float f) {
    unsigned int u = __float_as_uint(f);
    u += 0x7fffu + ((u >> 16) & 1u);   // RNE
    return (unsigned short)(u >> 16);
}
__device__ __forceinline__ float bfu2f_lo(unsigned int v) { return __uint_as_float(v << 16); }
__device__ __forceinline__ float bfu2f_hi(unsigned int v) { return __uint_as_float(v & 0xffff0000u); }

// ---------------- CSR build ----------------

__global__ void hist_kernel(const int* __restrict__ dst, int* __restrict__ counts,
                            int* __restrict__ rank) {
    int e = blockIdx.x * blockDim.x + threadIdx.x;
    if (e < N_EDGES) rank[e] = atomicAdd(&counts[dst[e]], 1);
}

#define SCAN_NB ((N_NODES + 255) / 256)   // 196 blocks

__global__ void scan_partial(const int* __restrict__ counts, int* __restrict__ block_sums) {
    __shared__ int sd[256];
    int i = blockIdx.x * 256 + threadIdx.x;
    sd[threadIdx.x] = (i < N_NODES) ? counts[i] : 0;
    __syncthreads();
    for (int off = 128; off > 0; off >>= 1) {
        if (threadIdx.x < off) sd[threadIdx.x] += sd[threadIdx.x + off];
        __syncthreads();
    }
    if (threadIdx.x == 0) block_sums[blockIdx.x] = sd[0];
}

__global__ void scan_block_sums(const int* __restrict__ block_sums, int* __restrict__ block_offsets) {
    __shared__ int sd[256];
    int v = (threadIdx.x < SCAN_NB) ? block_sums[threadIdx.x] : 0;
    sd[threadIdx.x] = v;
    __syncthreads();
    for (int off = 1; off < 256; off <<= 1) {
        int t = (threadIdx.x >= off) ? sd[threadIdx.x - off] : 0;
        __syncthreads();
        sd[threadIdx.x] += t;
        __syncthreads();
    }
    if (threadIdx.x < SCAN_NB) block_offsets[threadIdx.x] = sd[threadIdx.x] - v;
}

__global__ void scan_final(const int* __restrict__ counts, const int* __restrict__ block_offsets,
                           int* __restrict__ offsets) {
    __shared__ int sd[256];
    int i = blockIdx.x * 256 + threadIdx.x;
    int v = (i < N_NODES) ? counts[i] : 0;
    sd[threadIdx.x] = v;
    __syncthreads();
    for (int off = 1; off < 256; off <<= 1) {
        int t = (threadIdx.x >= off) ? sd[threadIdx.x - off] : 0;
        __syncthreads();
        sd[threadIdx.x] += t;
        __syncthreads();
    }
    if (i < N_NODES) offsets[i + 1] = block_offsets[blockIdx.x] + sd[threadIdx.x];
    if (i == 0) offsets[0] = 0;
}

__global__ void bucket_kernel(const int* __restrict__ src, const int* __restrict__ dst,
                              const int* __restrict__ offsets, const int* __restrict__ rank,
                              int* __restrict__ srcs_sorted) {
    int e = blockIdx.x * blockDim.x + threadIdx.x;
    if (e < N_EDGES) {
        int d = dst[e];
        srcs_sorted[offsets[d] + rank[e]] = src[e];
    }
}

// ---------------- dtype prep (x and W in one dispatch) ----------------

#define CVT_X_T (N_NODES * (DIM / 4))     // 1,600,000 float4s
#define CVT_W_T (6 * DIM * DIM)           // 98,304 elements

__global__ void cvt_kernel(const float* __restrict__ x, unsigned short* __restrict__ z,
                           const float* __restrict__ Ws1, const float* __restrict__ Ws2,
                           unsigned short* __restrict__ wt) {
    int t = blockIdx.x * blockDim.x + threadIdx.x;
    if (t < CVT_X_T) {
        float4 v = ((const float4*)x)[t];
        ushort4 o;
        o.x = f2bf(v.x); o.y = f2bf(v.y); o.z = f2bf(v.z); o.w = f2bf(v.w);
        ((ushort4*)z)[t] = o;
    } else if (t - CVT_X_T < CVT_W_T) {
        int u = t - CVT_X_T;
        int m = u >> 14;
        int r = u & 16383;
        int n = r >> 7;
        int k = r & 127;
        const float* Wm = (m < 3) ? (Ws1 + (size_t)m * DIM * DIM) : (Ws2 + (size_t)(m - 3) * DIM * DIM);
        wt[u] = f2bf(Wm[(size_t)k * DIM + n]);   // WT[m][n][k]
    }
}

// ---------------- fused layer: z' = relu(relu((z_i + sum_j z_j)@W1+b1)@W2+b2) ----
// Block = 256 (4 waves), 64 rows/block, wave owns 16 rows for ALL phases:
//   phase 1: per-row CSR gather, fp32 accumulate, pack bf16 -> h_lds (A-layout)
//   phase 2: GEMM1 from h_lds, relu+bias -> t_lds
//   phase 3: GEMM2 from t_lds, relu+bias -> global (bf16, or fp32 if LAST)
// LDS stride 132 bf16 (66 dw): uint writes land 2 lanes/bank (free, m136).

#define T_STRIDE 132

template <bool LAST>
__global__ __launch_bounds__(256) void layer_fused(const unsigned short* __restrict__ z,
                                                   const int* __restrict__ offsets,
                                                   const int* __restrict__ srcs,
                                                   const unsigned short* __restrict__ WT1,
                                                   const float* __restrict__ b1,
                                                   const unsigned short* __restrict__ WT2,
                                                   const float* __restrict__ b2,
                                                   void* __restrict__ Cout, int M) {
    __shared__ unsigned short h_lds[64 * T_STRIDE];
    __shared__ unsigned short t_lds[64 * T_STRIDE];
    int wave = threadIdx.x >> 6;
    int lane = threadIdx.x & 63;
    int quad = lane >> 4;
    int r16  = lane & 15;
    int rowbase = blockIdx.x * 64 + wave * 16;
    int lrow = wave * 16;
    const unsigned int* zp = (const unsigned int*)z;
    unsigned int* hl = (unsigned int*)h_lds;

    // ---- phase 1: gather 16 rows (lane owns cols 2*lane, 2*lane+1) ----
    for (int r = 0; r < 16; ++r) {
        int node = rowbase + r;
        if (node > M - 1) node = M - 1;
        unsigned int self = zp[(size_t)node * 64 + lane];
        float ax0 = bfu2f_lo(self), ay0 = bfu2f_hi(self);
        float ax1 = 0.f, ay1 = 0.f, ax2 = 0.f, ay2 = 0.f, ax3 = 0.f, ay3 = 0.f;
        float ax4 = 0.f, ay4 = 0.f, ax5 = 0.f, ay5 = 0.f, ax6 = 0.f, ay6 = 0.f, ax7 = 0.f, ay7 = 0.f;
        int s = offsets[node], e = offsets[node + 1];
        int i = s;
        for (; i + 8 <= e; i += 8) {
            int s0 = srcs[i + 0], s1 = srcs[i + 1], s2 = srcs[i + 2], s3 = srcs[i + 3];
            int s4 = srcs[i + 4], s5 = srcs[i + 5], s6 = srcs[i + 6], s7 = srcs[i + 7];
            unsigned int v0 = zp[(size_t)s0 * 64 + lane];
            unsigned int v1 = zp[(size_t)s1 * 64 + lane];
            unsigned int v2 = zp[(size_t)s2 * 64 + lane];
            unsigned int v3 = zp[(size_t)s3 * 64 + lane];
            unsigned int v4 = zp[(size_t)s4 * 64 + lane];
            unsigned int v5 = zp[(size_t)s5 * 64 + lane];
            unsigned int v6 = zp[(size_t)s6 * 64 + lane];
            unsigned int v7 = zp[(size_t)s7 * 64 + lane];
            ax0 += bfu2f_lo(v0); ay0 += bfu2f_hi(v0);
            ax1 += bfu2f_lo(v1); ay1 += bfu2f_hi(v1);
            ax2 += bfu2f_lo(v2); ay2 += bfu2f_hi(v2);
            ax3 += bfu2f_lo(v3); ay3 += bfu2f_hi(v3);
            ax4 += bfu2f_lo(v4); ay4 += bfu2f_hi(v4);
            ax5 += bfu2f_lo(v5); ay5 += bfu2f_hi(v5);
            ax6 += bfu2f_lo(v6); ay6 += bfu2f_hi(v6);
            ax7 += bfu2f_lo(v7); ay7 += bfu2f_hi(v7);
        }
        for (; i < e; ++i) {
            unsigned int v = zp[(size_t)srcs[i] * 64 + lane];
            ax0 += bfu2f_lo(v); ay0 += bfu2f_hi(v);
        }
        ax0 += ax1 + ax2 + ax3 + ax4 + ax5 + ax6 + ax7;
        ay0 += ay1 + ay2 + ay3 + ay4 + ay5 + ay6 + ay7;
        hl[(lrow + r) * (T_STRIDE / 2) + lane] =
            (unsigned int)f2bf(ax0) | ((unsigned int)f2bf(ay0) << 16);
    }
    __syncthreads();

    // ---- phase 2: GEMM1 (16x128 @ 128x128) from h_lds ----
    f32x4 acc[8];
#pragma unroll
    for (int nt = 0; nt < 8; ++nt)
#pragma unroll
        for (int i = 0; i < 4; ++i) acc[nt][i] = 0.f;

#pragma unroll
    for (int ks = 0; ks < 4; ++ks) {
        int k = ks * 32 + quad * 8;
        bf16x8 a = *(const bf16x8*)&h_lds[(lrow + r16) * T_STRIDE + k];
#pragma unroll
        for (int nt = 0; nt < 8; ++nt) {
            bf16x8 b = *(const bf16x8*)(WT1 + (size_t)(nt * 16 + r16) * DIM + k);
            acc[nt] = __builtin_amdgcn_mfma_f32_16x16x32_bf16(a, b, acc[nt], 0, 0, 0);
        }
    }

#pragma unroll
    for (int nt = 0; nt < 8; ++nt) {
        int col = nt * 16 + r16;
        float bv = b1[col];
#pragma unroll
        for (int i = 0; i < 4; ++i) {
            float v = fmaxf(acc[nt][i] + bv, 0.f);
            t_lds[(lrow + quad * 4 + i) * T_STRIDE + col] = f2bf(v);
        }
    }
    __syncthreads();

    // ---- phase 3: GEMM2 from t_lds -> global ----
    f32x4 acc2[8];
#pragma unroll
    for (int nt = 0; nt < 8; ++nt)
#pragma unroll
        for (int i = 0; i < 4; ++i) acc2[nt][i] = 0.f;

#pragma unroll
    for (int ks = 0; ks < 4; ++ks) {
        int k = ks * 32 + quad * 8;
        bf16x8 a = *(const bf16x8*)&t_lds[(lrow + r16) * T_STRIDE + k];
#pragma unroll
        for (int nt = 0; nt < 8; ++nt) {
            bf16x8 b = *(const bf16x8*)(WT2 + (size_t)(nt * 16 + r16) * DIM + k);
            acc2[nt] = __builtin_amdgcn_mfma_f32_16x16x32_bf16(a, b, acc2[nt], 0, 0, 0);
        }
    }

#pragma unroll
    for (int nt = 0; nt < 8; ++nt) {
        int col = nt * 16 + r16;
        float bv = b2[col];
#pragma unroll
        for (int i = 0; i < 4; ++i) {
            int row = rowbase + quad * 4 + i;
            if (row < M) {
                float v = fmaxf(acc2[nt][i] + bv, 0.f);
                if (LAST) ((float*)Cout)[(size_t)row * DIM + col] = v;
                else ((unsigned short*)Cout)[(size_t)row * DIM + col] = f2bf(v);
            }
        }
    }
}

// ---------------- launch ----------------

extern "C" void kernel_launch(void* const* d_in, const int* in_sizes, int n_in,
                              void* d_out, int out_size, void* d_ws, size_t ws_size,
                              hipStream_t stream) {
    const float* x   = (const float*)d_in[0];
    const float* Ws1 = (const float*)d_in[1];
    const float* bs1 = (const float*)d_in[2];
    const float* Ws2 = (const float*)d_in[3];
    const float* bs2 = (const float*)d_in[4];
    const int*   ei  = (const int*)d_in[5];   // int32 (JAX x64 disabled)
    const int* src = ei;
    const int* dst = ei + N_EDGES;
    float* out = (float*)d_out;

    char* ws = (char*)d_ws;
    size_t off = 0;
    auto carve = [&](size_t bytes) {
        void* p = ws + off;
        off += (bytes + 255) & ~(size_t)255;
        return p;
    };
    unsigned short* zA   = (unsigned short*)carve((size_t)N_NODES * DIM * 2);
    unsigned short* zB   = (unsigned short*)carve((size_t)N_NODES * DIM * 2);
    unsigned short* wt   = (unsigned short*)carve((size_t)6 * DIM * DIM * 2);
    int* counts  = (int*)carve((size_t)N_NODES * 4);
    int* offsets = (int*)carve((size_t)(N_NODES + 1) * 4);
    int* rank    = (int*)carve((size_t)N_EDGES * 4);
    int* srcs    = (int*)carve((size_t)N_EDGES * 4);
    int* bsums   = (int*)carve((size_t)SCAN_NB * 4);
    int* boffs   = (int*)carve((size_t)SCAN_NB * 4);

    // CSR build
    hipMemsetAsync(counts, 0, (size_t)N_NODES * 4, stream);
    hist_kernel<<<(N_EDGES + 255) / 256, 256, 0, stream>>>(dst, counts, rank);
    scan_partial<<<SCAN_NB, 256, 0, stream>>>(counts, bsums);
    scan_block_sums<<<1, 256, 0, stream>>>(bsums, boffs);
    scan_final<<<SCAN_NB, 256, 0, stream>>>(counts, boffs, offsets);
    bucket_kernel<<<(N_EDGES + 255) / 256, 256, 0, stream>>>(src, dst, offsets, rank, srcs);

    // dtype prep (one dispatch)
    cvt_kernel<<<(CVT_X_T + CVT_W_T + 255) / 256, 256, 0, stream>>>(x, zA, Ws1, Ws2, wt);

    const int grid = (N_NODES + 63) / 64;

    unsigned short* zin = zA;
    unsigned short* znext = zB;
    for (int l = 0; l < N_LAYERS; ++l) {
        if (l == N_LAYERS - 1) {
            layer_fused<true><<<grid, 256, 0, stream>>>(
                zin, offsets, srcs,
                wt + (size_t)l * DIM * DIM, bs1 + (size_t)l * DIM,
                wt + (size_t)(3 + l) * DIM * DIM, bs2 + (size_t)l * DIM, out, N_NODES);
        } else {
            layer_fused<false><<<grid, 256, 0, stream>>>(
                zin, offsets, srcs,
                wt + (size_t)l * DIM * DIM, bs1 + (size_t)l * DIM,
                wt + (size_t)(3 + l) * DIM * DIM, bs2 + (size_t)l * DIM, znext, N_NODES);
            unsigned short* tmp = zin; zin = znext; znext = tmp;
        }
    }
}

// Round 6
// 352.078 us; speedup vs baseline: 1.2206x; 1.2206x over previous
//
#include <hip/hip_runtime.h>

#define N_NODES 50000
#define N_EDGES 800000
#define DIM 128
#define N_LAYERS 3

typedef __attribute__((ext_vector_type(8))) short bf16x8;
typedef __attribute__((ext_vector_type(4))) float f32x4;

__device__ __forceinline__ unsigned short f2bf(float f) {
    unsigned int u = __float_as_uint(f);
    u += 0x7fffu + ((u >> 16) & 1u);   // RNE
    return (unsigned short)(u >> 16);
}
__device__ __forceinline__ float bfu2f_lo(unsigned int v) { return __uint_as_float(v << 16); }
__device__ __forceinline__ float bfu2f_hi(unsigned int v) { return __uint_as_float(v & 0xffff0000u); }

// ---------------- CSR build ----------------

__global__ void hist_kernel(const int* __restrict__ dst, int* __restrict__ counts,
                            int* __restrict__ rank) {
    int e = blockIdx.x * blockDim.x + threadIdx.x;
    if (e < N_EDGES) rank[e] = atomicAdd(&counts[dst[e]], 1);
}

#define SCAN_NB ((N_NODES + 255) / 256)   // 196 blocks

__global__ void scan_partial(const int* __restrict__ counts, int* __restrict__ block_sums) {
    __shared__ int sd[256];
    int i = blockIdx.x * 256 + threadIdx.x;
    sd[threadIdx.x] = (i < N_NODES) ? counts[i] : 0;
    __syncthreads();
    for (int off = 128; off > 0; off >>= 1) {
        if (threadIdx.x < off) sd[threadIdx.x] += sd[threadIdx.x + off];
        __syncthreads();
    }
    if (threadIdx.x == 0) block_sums[blockIdx.x] = sd[0];
}

__global__ void scan_block_sums(const int* __restrict__ block_sums, int* __restrict__ block_offsets) {
    __shared__ int sd[256];
    int v = (threadIdx.x < SCAN_NB) ? block_sums[threadIdx.x] : 0;
    sd[threadIdx.x] = v;
    __syncthreads();
    for (int off = 1; off < 256; off <<= 1) {
        int t = (threadIdx.x >= off) ? sd[threadIdx.x - off] : 0;
        __syncthreads();
        sd[threadIdx.x] += t;
        __syncthreads();
    }
    if (threadIdx.x < SCAN_NB) block_offsets[threadIdx.x] = sd[threadIdx.x] - v;
}

__global__ void scan_final(const int* __restrict__ counts, const int* __restrict__ block_offsets,
                           int* __restrict__ offsets) {
    __shared__ int sd[256];
    int i = blockIdx.x * 256 + threadIdx.x;
    int v = (i < N_NODES) ? counts[i] : 0;
    sd[threadIdx.x] = v;
    __syncthreads();
    for (int off = 1; off < 256; off <<= 1) {
        int t = (threadIdx.x >= off) ? sd[threadIdx.x - off] : 0;
        __syncthreads();
        sd[threadIdx.x] += t;
        __syncthreads();
    }
    if (i < N_NODES) offsets[i + 1] = block_offsets[blockIdx.x] + sd[threadIdx.x];
    if (i == 0) offsets[0] = 0;
}

// 2 edges/thread (independent chains), nontemporal scattered store
#define BUCKET_HALF (N_EDGES / 2)

__global__ void bucket_kernel(const int* __restrict__ src, const int* __restrict__ dst,
                              const int* __restrict__ offsets, const int* __restrict__ rank,
                              int* __restrict__ srcs_sorted) {
    int e = blockIdx.x * blockDim.x + threadIdx.x;
    if (e < BUCKET_HALF) {
        int e1 = e + BUCKET_HALF;
        int d0 = dst[e];
        int d1 = dst[e1];
        int r0 = rank[e];
        int r1 = rank[e1];
        int s0 = src[e];
        int s1 = src[e1];
        int o0 = offsets[d0];
        int o1 = offsets[d1];
        __builtin_nontemporal_store(s0, &srcs_sorted[o0 + r0]);
        __builtin_nontemporal_store(s1, &srcs_sorted[o1 + r1]);
    }
}

// ---------------- dtype prep (x and W in one dispatch) ----------------

#define CVT_X_T (N_NODES * (DIM / 4))     // 1,600,000 float4s
#define CVT_W_T (6 * DIM * DIM)           // 98,304 elements

__global__ void cvt_kernel(const float* __restrict__ x, unsigned short* __restrict__ z,
                           const float* __restrict__ Ws1, const float* __restrict__ Ws2,
                           unsigned short* __restrict__ wt) {
    int t = blockIdx.x * blockDim.x + threadIdx.x;
    if (t < CVT_X_T) {
        float4 v = ((const float4*)x)[t];
        ushort4 o;
        o.x = f2bf(v.x); o.y = f2bf(v.y); o.z = f2bf(v.z); o.w = f2bf(v.w);
        ((ushort4*)z)[t] = o;
    } else if (t - CVT_X_T < CVT_W_T) {
        int u = t - CVT_X_T;
        int m = u >> 14;
        int r = u & 16383;
        int n = r >> 7;
        int k = r & 127;
        const float* Wm = (m < 3) ? (Ws1 + (size_t)m * DIM * DIM) : (Ws2 + (size_t)(m - 3) * DIM * DIM);
        wt[u] = f2bf(Wm[(size_t)k * DIM + n]);   // WT[m][n][k]
    }
}

// ---------------- aggregation (one wave per node — max TLP for latency hiding) ----

__global__ __launch_bounds__(256) void agg_kernel(const unsigned short* __restrict__ z,
                                                  const int* __restrict__ offsets,
                                                  const int* __restrict__ srcs,
                                                  unsigned short* __restrict__ h) {
    int gid  = blockIdx.x * blockDim.x + threadIdx.x;
    int node = gid >> 6;
    int lane = threadIdx.x & 63;
    if (node >= N_NODES) return;
    const unsigned int* zp = (const unsigned int*)z;
    unsigned int self = zp[(size_t)node * 64 + lane];
    float ax0 = bfu2f_lo(self), ay0 = bfu2f_hi(self);
    float ax1 = 0.f, ay1 = 0.f, ax2 = 0.f, ay2 = 0.f, ax3 = 0.f, ay3 = 0.f;
    float ax4 = 0.f, ay4 = 0.f, ax5 = 0.f, ay5 = 0.f, ax6 = 0.f, ay6 = 0.f, ax7 = 0.f, ay7 = 0.f;
    int s = offsets[node], e = offsets[node + 1];
    int i = s;
    for (; i + 8 <= e; i += 8) {
        int s0 = srcs[i + 0], s1 = srcs[i + 1], s2 = srcs[i + 2], s3 = srcs[i + 3];
        int s4 = srcs[i + 4], s5 = srcs[i + 5], s6 = srcs[i + 6], s7 = srcs[i + 7];
        unsigned int v0 = zp[(size_t)s0 * 64 + lane];
        unsigned int v1 = zp[(size_t)s1 * 64 + lane];
        unsigned int v2 = zp[(size_t)s2 * 64 + lane];
        unsigned int v3 = zp[(size_t)s3 * 64 + lane];
        unsigned int v4 = zp[(size_t)s4 * 64 + lane];
        unsigned int v5 = zp[(size_t)s5 * 64 + lane];
        unsigned int v6 = zp[(size_t)s6 * 64 + lane];
        unsigned int v7 = zp[(size_t)s7 * 64 + lane];
        ax0 += bfu2f_lo(v0); ay0 += bfu2f_hi(v0);
        ax1 += bfu2f_lo(v1); ay1 += bfu2f_hi(v1);
        ax2 += bfu2f_lo(v2); ay2 += bfu2f_hi(v2);
        ax3 += bfu2f_lo(v3); ay3 += bfu2f_hi(v3);
        ax4 += bfu2f_lo(v4); ay4 += bfu2f_hi(v4);
        ax5 += bfu2f_lo(v5); ay5 += bfu2f_hi(v5);
        ax6 += bfu2f_lo(v6); ay6 += bfu2f_hi(v6);
        ax7 += bfu2f_lo(v7); ay7 += bfu2f_hi(v7);
    }
    for (; i < e; ++i) {
        unsigned int v = zp[(size_t)srcs[i] * 64 + lane];
        ax0 += bfu2f_lo(v); ay0 += bfu2f_hi(v);
    }
    ax0 += ax1 + ax2 + ax3 + ax4 + ax5 + ax6 + ax7;
    ay0 += ay1 + ay2 + ay3 + ay4 + ay5 + ay6 + ay7;
    unsigned int packed = (unsigned int)f2bf(ax0) | ((unsigned int)f2bf(ay0) << 16);
    ((unsigned int*)h)[(size_t)node * 64 + lane] = packed;
}

// ---------------- fused MLP: C = relu(relu(A@W1+b1)@W2+b2) ----------------
// Block = 128 threads (2 waves), 64 rows/block, wave tile 32 rows x 128 cols
// (2 m-tiles share each B-fragment -> 2x W-load reuse vs 16-row waves).
// Intermediate t via LDS (stride 132 bf16: conflict-free, m136).

#define T_STRIDE 132

template <bool LAST>
__global__ __launch_bounds__(128) void mlp_fused(const unsigned short* __restrict__ A,
                                                 const unsigned short* __restrict__ WT1,
                                                 const float* __restrict__ b1,
                                                 const unsigned short* __restrict__ WT2,
                                                 const float* __restrict__ b2,
                                                 void* __restrict__ Cout, int M) {
    __shared__ unsigned short t_lds[64 * T_STRIDE];
    int wave = threadIdx.x >> 6;     // 0..1
    int lane = threadIdx.x & 63;
    int quad = lane >> 4;
    int r16  = lane & 15;
    int rowbase = blockIdx.x * 64 + wave * 32;
    int lrow = wave * 32;

    // ---- GEMM1: acc = A(32x128) @ W1 ----
    f32x4 acc[2][8];
#pragma unroll
    for (int mt = 0; mt < 2; ++mt)
#pragma unroll
        for (int nt = 0; nt < 8; ++nt)
#pragma unroll
            for (int i = 0; i < 4; ++i) acc[mt][nt][i] = 0.f;

    int ar0 = rowbase + r16;       if (ar0 > M - 1) ar0 = M - 1;
    int ar1 = rowbase + 16 + r16;  if (ar1 > M - 1) ar1 = M - 1;

#pragma unroll
    for (int ks = 0; ks < 4; ++ks) {
        int k = ks * 32 + quad * 8;
        bf16x8 a0 = *(const bf16x8*)(A + (size_t)ar0 * DIM + k);
        bf16x8 a1 = *(const bf16x8*)(A + (size_t)ar1 * DIM + k);
#pragma unroll
        for (int nt = 0; nt < 8; ++nt) {
            bf16x8 b = *(const bf16x8*)(WT1 + (size_t)(nt * 16 + r16) * DIM + k);
            acc[0][nt] = __builtin_amdgcn_mfma_f32_16x16x32_bf16(a0, b, acc[0][nt], 0, 0, 0);
            acc[1][nt] = __builtin_amdgcn_mfma_f32_16x16x32_bf16(a1, b, acc[1][nt], 0, 0, 0);
        }
    }

    // ---- epilogue1: t = relu(acc + b1) -> LDS ----
#pragma unroll
    for (int mt = 0; mt < 2; ++mt)
#pragma unroll
        for (int nt = 0; nt < 8; ++nt) {
            int col = nt * 16 + r16;
            float bv = b1[col];
#pragma unroll
            for (int i = 0; i < 4; ++i) {
                float v = fmaxf(acc[mt][nt][i] + bv, 0.f);
                t_lds[(lrow + mt * 16 + quad * 4 + i) * T_STRIDE + col] = f2bf(v);
            }
        }
    __syncthreads();

    // ---- GEMM2: acc2 = t(32x128) @ W2 ----
    f32x4 acc2[2][8];
#pragma unroll
    for (int mt = 0; mt < 2; ++mt)
#pragma unroll
        for (int nt = 0; nt < 8; ++nt)
#pragma unroll
            for (int i = 0; i < 4; ++i) acc2[mt][nt][i] = 0.f;

#pragma unroll
    for (int ks = 0; ks < 4; ++ks) {
        int k = ks * 32 + quad * 8;
        bf16x8 a0 = *(const bf16x8*)&t_lds[(lrow + r16) * T_STRIDE + k];
        bf16x8 a1 = *(const bf16x8*)&t_lds[(lrow + 16 + r16) * T_STRIDE + k];
#pragma unroll
        for (int nt = 0; nt < 8; ++nt) {
            bf16x8 b = *(const bf16x8*)(WT2 + (size_t)(nt * 16 + r16) * DIM + k);
            acc2[0][nt] = __builtin_amdgcn_mfma_f32_16x16x32_bf16(a0, b, acc2[0][nt], 0, 0, 0);
            acc2[1][nt] = __builtin_amdgcn_mfma_f32_16x16x32_bf16(a1, b, acc2[1][nt], 0, 0, 0);
        }
    }

    // ---- epilogue2: z = relu(acc2 + b2) -> global ----
#pragma unroll
    for (int mt = 0; mt < 2; ++mt)
#pragma unroll
        for (int nt = 0; nt < 8; ++nt) {
            int col = nt * 16 + r16;
            float bv = b2[col];
#pragma unroll
            for (int i = 0; i < 4; ++i) {
                int row = rowbase + mt * 16 + quad * 4 + i;
                if (row < M) {
                    float v = fmaxf(acc2[mt][nt][i] + bv, 0.f);
                    if (LAST) ((float*)Cout)[(size_t)row * DIM + col] = v;
                    else ((unsigned short*)Cout)[(size_t)row * DIM + col] = f2bf(v);
                }
            }
        }
}

// ---------------- launch ----------------

extern "C" void kernel_launch(void* const* d_in, const int* in_sizes, int n_in,
                              void* d_out, int out_size, void* d_ws, size_t ws_size,
                              hipStream_t stream) {
    const float* x   = (const float*)d_in[0];
    const float* Ws1 = (const float*)d_in[1];
    const float* bs1 = (const float*)d_in[2];
    const float* Ws2 = (const float*)d_in[3];
    const float* bs2 = (const float*)d_in[4];
    const int*   ei  = (const int*)d_in[5];   // int32 (JAX x64 disabled)
    const int* src = ei;
    const int* dst = ei + N_EDGES;
    float* out = (float*)d_out;

    char* ws = (char*)d_ws;
    size_t off = 0;
    auto carve = [&](size_t bytes) {
        void* p = ws + off;
        off += (bytes + 255) & ~(size_t)255;
        return p;
    };
    unsigned short* zA   = (unsigned short*)carve((size_t)N_NODES * DIM * 2);
    unsigned short* zB   = (unsigned short*)carve((size_t)N_NODES * DIM * 2);
    unsigned short* bufh = (unsigned short*)carve((size_t)N_NODES * DIM * 2);
    unsigned short* wt   = (unsigned short*)carve((size_t)6 * DIM * DIM * 2);
    int* counts  = (int*)carve((size_t)N_NODES * 4);
    int* offsets = (int*)carve((size_t)(N_NODES + 1) * 4);
    int* rank    = (int*)carve((size_t)N_EDGES * 4);
    int* srcs    = (int*)carve((size_t)N_EDGES * 4);
    int* bsums   = (int*)carve((size_t)SCAN_NB * 4);
    int* boffs   = (int*)carve((size_t)SCAN_NB * 4);

    // CSR build
    hipMemsetAsync(counts, 0, (size_t)N_NODES * 4, stream);
    hist_kernel<<<(N_EDGES + 255) / 256, 256, 0, stream>>>(dst, counts, rank);
    scan_partial<<<SCAN_NB, 256, 0, stream>>>(counts, bsums);
    scan_block_sums<<<1, 256, 0, stream>>>(bsums, boffs);
    scan_final<<<SCAN_NB, 256, 0, stream>>>(counts, boffs, offsets);
    bucket_kernel<<<(BUCKET_HALF + 255) / 256, 256, 0, stream>>>(src, dst, offsets, rank, srcs);

    // dtype prep (one dispatch)
    cvt_kernel<<<(CVT_X_T + CVT_W_T + 255) / 256, 256, 0, stream>>>(x, zA, Ws1, Ws2, wt);

    const int agg_grid = (N_NODES * 64 + 255) / 256;
    const int mlp_grid = (N_NODES + 63) / 64;

    unsigned short* zin = zA;
    unsigned short* znext = zB;
    for (int l = 0; l < N_LAYERS; ++l) {
        agg_kernel<<<agg_grid, 256, 0, stream>>>(zin, offsets, srcs, bufh);
        if (l == N_LAYERS - 1) {
            mlp_fused<true><<<mlp_grid, 128, 0, stream>>>(
                bufh, wt + (size_t)l * DIM * DIM, bs1 + (size_t)l * DIM,
                wt + (size_t)(3 + l) * DIM * DIM, bs2 + (size_t)l * DIM, out, N_NODES);
        } else {
            mlp_fused<false><<<mlp_grid, 128, 0, stream>>>(
                bufh, wt + (size_t)l * DIM * DIM, bs1 + (size_t)l * DIM,
                wt + (size_t)(3 + l) * DIM * DIM, bs2 + (size_t)l * DIM, znext, N_NODES);
            unsigned short* tmp = zin; zin = znext; znext = tmp;
        }
    }
}

// Round 7
// 336.646 us; speedup vs baseline: 1.2766x; 1.0458x over previous
//
#include <hip/hip_runtime.h>

#define N_NODES 50000
#define N_EDGES 800000
#define DIM 128
#define N_LAYERS 3

typedef __attribute__((ext_vector_type(8))) short bf16x8;
typedef __attribute__((ext_vector_type(4))) float f32x4;

__device__ __forceinline__ unsigned short f2bf(float f) {
    unsigned int u = __float_as_uint(f);
    u += 0x7fffu + ((u >> 16) & 1u);   // RNE
    return (unsigned short)(u >> 16);
}
__device__ __forceinline__ float bfu2f_lo(unsigned int v) { return __uint_as_float(v << 16); }
__device__ __forceinline__ float bfu2f_hi(unsigned int v) { return __uint_as_float(v & 0xffff0000u); }

// ---------------- CSR build + dtype prep ----------------

#define SCAN_NB ((N_NODES + 255) / 256)       // 196
#define HIST_NB ((N_EDGES + 255) / 256)       // 3125
#define CVT_X_T (N_NODES * (DIM / 4))         // 1,600,000 float4s
#define CVT_W_T (6 * DIM * DIM)               // 98,304
#define CVT_NB  ((CVT_X_T + CVT_W_T + 255) / 256)

// hist (rank-emitting) and x/W bf16 conversion are independent: one dispatch.
__global__ void hist_cvt_kernel(const int* __restrict__ dst, int* __restrict__ counts,
                                int* __restrict__ rank,
                                const float* __restrict__ x, unsigned short* __restrict__ z,
                                const float* __restrict__ Ws1, const float* __restrict__ Ws2,
                                unsigned short* __restrict__ wt) {
    if (blockIdx.x < HIST_NB) {
        int e = blockIdx.x * 256 + threadIdx.x;
        if (e < N_EDGES) rank[e] = atomicAdd(&counts[dst[e]], 1);
    } else {
        int t = (blockIdx.x - HIST_NB) * 256 + threadIdx.x;
        if (t < CVT_X_T) {
            float4 v = ((const float4*)x)[t];
            ushort4 o;
            o.x = f2bf(v.x); o.y = f2bf(v.y); o.z = f2bf(v.z); o.w = f2bf(v.w);
            ((ushort4*)z)[t] = o;
        } else if (t - CVT_X_T < CVT_W_T) {
            int u = t - CVT_X_T;
            int m = u >> 14;
            int r = u & 16383;
            int n = r >> 7;
            int k = r & 127;
            const float* Wm = (m < 3) ? (Ws1 + (size_t)m * DIM * DIM)
                                      : (Ws2 + (size_t)(m - 3) * DIM * DIM);
            wt[u] = f2bf(Wm[(size_t)k * DIM + n]);   // WT[m][n][k]
        }
    }
}

__global__ void scan_partial(const int* __restrict__ counts, int* __restrict__ block_sums) {
    __shared__ int sd[256];
    int i = blockIdx.x * 256 + threadIdx.x;
    sd[threadIdx.x] = (i < N_NODES) ? counts[i] : 0;
    __syncthreads();
    for (int off = 128; off > 0; off >>= 1) {
        if (threadIdx.x < off) sd[threadIdx.x] += sd[threadIdx.x + off];
        __syncthreads();
    }
    if (threadIdx.x == 0) block_sums[blockIdx.x] = sd[0];
}

__global__ void scan_block_sums(const int* __restrict__ block_sums, int* __restrict__ block_offsets) {
    __shared__ int sd[256];
    int v = (threadIdx.x < SCAN_NB) ? block_sums[threadIdx.x] : 0;
    sd[threadIdx.x] = v;
    __syncthreads();
    for (int off = 1; off < 256; off <<= 1) {
        int t = (threadIdx.x >= off) ? sd[threadIdx.x - off] : 0;
        __syncthreads();
        sd[threadIdx.x] += t;
        __syncthreads();
    }
    if (threadIdx.x < SCAN_NB) block_offsets[threadIdx.x] = sd[threadIdx.x] - v;
}

__global__ void scan_final(const int* __restrict__ counts, const int* __restrict__ block_offsets,
                           int* __restrict__ offsets) {
    __shared__ int sd[256];
    int i = blockIdx.x * 256 + threadIdx.x;
    int v = (i < N_NODES) ? counts[i] : 0;
    sd[threadIdx.x] = v;
    __syncthreads();
    for (int off = 1; off < 256; off <<= 1) {
        int t = (threadIdx.x >= off) ? sd[threadIdx.x - off] : 0;
        __syncthreads();
        sd[threadIdx.x] += t;
        __syncthreads();
    }
    if (i < N_NODES) offsets[i + 1] = block_offsets[blockIdx.x] + sd[threadIdx.x];
    if (i == 0) offsets[0] = 0;
}

#define BUCKET_HALF (N_EDGES / 2)

__global__ void bucket_kernel(const int* __restrict__ src, const int* __restrict__ dst,
                              const int* __restrict__ offsets, const int* __restrict__ rank,
                              int* __restrict__ srcs_sorted) {
    int e = blockIdx.x * blockDim.x + threadIdx.x;
    if (e < BUCKET_HALF) {
        int e1 = e + BUCKET_HALF;
        int d0 = dst[e];
        int d1 = dst[e1];
        int r0 = rank[e];
        int r1 = rank[e1];
        int s0 = src[e];
        int s1 = src[e1];
        int o0 = offsets[d0];
        int o1 = offsets[d1];
        __builtin_nontemporal_store(s0, &srcs_sorted[o0 + r0]);
        __builtin_nontemporal_store(s1, &srcs_sorted[o1 + r1]);
    }
}

// ---------------- aggregation ----------------
// One wave per node (max TLP). Lane layout: half = lane>>5, col = lane&31.
// Each lane loads uint2 (8 B = 4 bf16); 32 lanes cover one 256 B row, so each
// gather instruction fetches TWO edge rows (edges i and i+1). Unroll 4 pairs
// = 8 rows in flight with half the VMEM instructions of the uint version.
// Cross-half combine: 4 shfl_xor(32); half 0 stores the packed row.

__global__ __launch_bounds__(256) void agg_kernel(const unsigned short* __restrict__ z,
                                                  const int* __restrict__ offsets,
                                                  const int* __restrict__ srcs,
                                                  unsigned short* __restrict__ h) {
    int gid  = blockIdx.x * blockDim.x + threadIdx.x;
    int node = gid >> 6;
    int lane = threadIdx.x & 63;
    int half = lane >> 5;
    int col  = lane & 31;
    if (node >= N_NODES) return;
    const uint2* zp = (const uint2*)z;

    float a0 = 0.f, a1 = 0.f, a2 = 0.f, a3 = 0.f;     // set A
    float b0 = 0.f, b1 = 0.f, b2 = 0.f, b3 = 0.f;     // set B
    float c0 = 0.f, c1 = 0.f, c2 = 0.f, c3 = 0.f;     // set C
    float d0 = 0.f, d1 = 0.f, d2 = 0.f, d3 = 0.f;     // set D

    int s = offsets[node], e = offsets[node + 1];
    int i = s;
    for (; i + 8 <= e; i += 8) {
        int e0 = srcs[i + 0 + half];
        int e1 = srcs[i + 2 + half];
        int e2 = srcs[i + 4 + half];
        int e3 = srcs[i + 6 + half];
        uint2 v0 = zp[(size_t)e0 * 32 + col];
        uint2 v1 = zp[(size_t)e1 * 32 + col];
        uint2 v2 = zp[(size_t)e2 * 32 + col];
        uint2 v3 = zp[(size_t)e3 * 32 + col];
        a0 += bfu2f_lo(v0.x); a1 += bfu2f_hi(v0.x); a2 += bfu2f_lo(v0.y); a3 += bfu2f_hi(v0.y);
        b0 += bfu2f_lo(v1.x); b1 += bfu2f_hi(v1.x); b2 += bfu2f_lo(v1.y); b3 += bfu2f_hi(v1.y);
        c0 += bfu2f_lo(v2.x); c1 += bfu2f_hi(v2.x); c2 += bfu2f_lo(v2.y); c3 += bfu2f_hi(v2.y);
        d0 += bfu2f_lo(v3.x); d1 += bfu2f_hi(v3.x); d2 += bfu2f_lo(v3.y); d3 += bfu2f_hi(v3.y);
    }
    for (; i + 2 <= e; i += 2) {
        int e0 = srcs[i + half];
        uint2 v = zp[(size_t)e0 * 32 + col];
        a0 += bfu2f_lo(v.x); a1 += bfu2f_hi(v.x); a2 += bfu2f_lo(v.y); a3 += bfu2f_hi(v.y);
    }
    if (i < e) {   // odd leftover edge: both halves load it, only half 0 counts it
        int e0 = srcs[i];
        uint2 v = zp[(size_t)e0 * 32 + col];
        if (half == 0) {
            a0 += bfu2f_lo(v.x); a1 += bfu2f_hi(v.x); a2 += bfu2f_lo(v.y); a3 += bfu2f_hi(v.y);
        }
    }

    a0 += b0 + c0 + d0;
    a1 += b1 + c1 + d1;
    a2 += b2 + c2 + d2;
    a3 += b3 + c3 + d3;
    // fold the other half's edges in (both halves end up with the full sum)
    a0 += __shfl_xor(a0, 32);
    a1 += __shfl_xor(a1, 32);
    a2 += __shfl_xor(a2, 32);
    a3 += __shfl_xor(a3, 32);
    // self term (eps = 0)
    uint2 sv = zp[(size_t)node * 32 + col];
    a0 += bfu2f_lo(sv.x); a1 += bfu2f_hi(sv.x);
    a2 += bfu2f_lo(sv.y); a3 += bfu2f_hi(sv.y);

    if (half == 0) {
        uint2 o;
        o.x = (unsigned int)f2bf(a0) | ((unsigned int)f2bf(a1) << 16);
        o.y = (unsigned int)f2bf(a2) | ((unsigned int)f2bf(a3) << 16);
        ((uint2*)h)[(size_t)node * 32 + col] = o;
    }
}

// ---------------- fused MLP: C = relu(relu(A@W1+b1)@W2+b2) ----------------
// Block = 128 threads (2 waves), 64 rows/block, wave tile 32 rows x 128 cols.

#define T_STRIDE 132

template <bool LAST>
__global__ __launch_bounds__(128) void mlp_fused(const unsigned short* __restrict__ A,
                                                 const unsigned short* __restrict__ WT1,
                                                 const float* __restrict__ b1,
                                                 const unsigned short* __restrict__ WT2,
                                                 const float* __restrict__ b2,
                                                 void* __restrict__ Cout, int M) {
    __shared__ unsigned short t_lds[64 * T_STRIDE];
    int wave = threadIdx.x >> 6;     // 0..1
    int lane = threadIdx.x & 63;
    int quad = lane >> 4;
    int r16  = lane & 15;
    int rowbase = blockIdx.x * 64 + wave * 32;
    int lrow = wave * 32;

    f32x4 acc[2][8];
#pragma unroll
    for (int mt = 0; mt < 2; ++mt)
#pragma unroll
        for (int nt = 0; nt < 8; ++nt)
#pragma unroll
            for (int i = 0; i < 4; ++i) acc[mt][nt][i] = 0.f;

    int ar0 = rowbase + r16;       if (ar0 > M - 1) ar0 = M - 1;
    int ar1 = rowbase + 16 + r16;  if (ar1 > M - 1) ar1 = M - 1;

#pragma unroll
    for (int ks = 0; ks < 4; ++ks) {
        int k = ks * 32 + quad * 8;
        bf16x8 a0 = *(const bf16x8*)(A + (size_t)ar0 * DIM + k);
        bf16x8 a1 = *(const bf16x8*)(A + (size_t)ar1 * DIM + k);
#pragma unroll
        for (int nt = 0; nt < 8; ++nt) {
            bf16x8 b = *(const bf16x8*)(WT1 + (size_t)(nt * 16 + r16) * DIM + k);
            acc[0][nt] = __builtin_amdgcn_mfma_f32_16x16x32_bf16(a0, b, acc[0][nt], 0, 0, 0);
            acc[1][nt] = __builtin_amdgcn_mfma_f32_16x16x32_bf16(a1, b, acc[1][nt], 0, 0, 0);
        }
    }

#pragma unroll
    for (int mt = 0; mt < 2; ++mt)
#pragma unroll
        for (int nt = 0; nt < 8; ++nt) {
            int col = nt * 16 + r16;
            float bv = b1[col];
#pragma unroll
            for (int i = 0; i < 4; ++i) {
                float v = fmaxf(acc[mt][nt][i] + bv, 0.f);
                t_lds[(lrow + mt * 16 + quad * 4 + i) * T_STRIDE + col] = f2bf(v);
            }
        }
    __syncthreads();

    f32x4 acc2[2][8];
#pragma unroll
    for (int mt = 0; mt < 2; ++mt)
#pragma unroll
        for (int nt = 0; nt < 8; ++nt)
#pragma unroll
            for (int i = 0; i < 4; ++i) acc2[mt][nt][i] = 0.f;

#pragma unroll
    for (int ks = 0; ks < 4; ++ks) {
        int k = ks * 32 + quad * 8;
        bf16x8 a0 = *(const bf16x8*)&t_lds[(lrow + r16) * T_STRIDE + k];
        bf16x8 a1 = *(const bf16x8*)&t_lds[(lrow + 16 + r16) * T_STRIDE + k];
#pragma unroll
        for (int nt = 0; nt < 8; ++nt) {
            bf16x8 b = *(const bf16x8*)(WT2 + (size_t)(nt * 16 + r16) * DIM + k);
            acc2[0][nt] = __builtin_amdgcn_mfma_f32_16x16x32_bf16(a0, b, acc2[0][nt], 0, 0, 0);
            acc2[1][nt] = __builtin_amdgcn_mfma_f32_16x16x32_bf16(a1, b, acc2[1][nt], 0, 0, 0);
        }
    }

#pragma unroll
    for (int mt = 0; mt < 2; ++mt)
#pragma unroll
        for (int nt = 0; nt < 8; ++nt) {
            int col = nt * 16 + r16;
            float bv = b2[col];
#pragma unroll
            for (int i = 0; i < 4; ++i) {
                int row = rowbase + mt * 16 + quad * 4 + i;
                if (row < M) {
                    float v = fmaxf(acc2[mt][nt][i] + bv, 0.f);
                    if (LAST) __builtin_nontemporal_store(v, &((float*)Cout)[(size_t)row * DIM + col]);
                    else ((unsigned short*)Cout)[(size_t)row * DIM + col] = f2bf(v);
                }
            }
        }
}

// ---------------- launch ----------------

extern "C" void kernel_launch(void* const* d_in, const int* in_sizes, int n_in,
                              void* d_out, int out_size, void* d_ws, size_t ws_size,
                              hipStream_t stream) {
    const float* x   = (const float*)d_in[0];
    const float* Ws1 = (const float*)d_in[1];
    const float* bs1 = (const float*)d_in[2];
    const float* Ws2 = (const float*)d_in[3];
    const float* bs2 = (const float*)d_in[4];
    const int*   ei  = (const int*)d_in[5];   // int32 (JAX x64 disabled)
    const int* src = ei;
    const int* dst = ei + N_EDGES;
    float* out = (float*)d_out;

    char* ws = (char*)d_ws;
    size_t off = 0;
    auto carve = [&](size_t bytes) {
        void* p = ws + off;
        off += (bytes + 255) & ~(size_t)255;
        return p;
    };
    unsigned short* zA   = (unsigned short*)carve((size_t)N_NODES * DIM * 2);
    unsigned short* zB   = (unsigned short*)carve((size_t)N_NODES * DIM * 2);
    unsigned short* bufh = (unsigned short*)carve((size_t)N_NODES * DIM * 2);
    unsigned short* wt   = (unsigned short*)carve((size_t)6 * DIM * DIM * 2);
    int* counts  = (int*)carve((size_t)N_NODES * 4);
    int* offsets = (int*)carve((size_t)(N_NODES + 1) * 4);
    int* rank    = (int*)carve((size_t)N_EDGES * 4);
    int* srcs    = (int*)carve((size_t)N_EDGES * 4);
    int* bsums   = (int*)carve((size_t)SCAN_NB * 4);
    int* boffs   = (int*)carve((size_t)SCAN_NB * 4);

    // CSR build + dtype prep
    hipMemsetAsync(counts, 0, (size_t)N_NODES * 4, stream);
    hist_cvt_kernel<<<HIST_NB + CVT_NB, 256, 0, stream>>>(dst, counts, rank, x, zA, Ws1, Ws2, wt);
    scan_partial<<<SCAN_NB, 256, 0, stream>>>(counts, bsums);
    scan_block_sums<<<1, 256, 0, stream>>>(bsums, boffs);
    scan_final<<<SCAN_NB, 256, 0, stream>>>(counts, boffs, offsets);
    bucket_kernel<<<(BUCKET_HALF + 255) / 256, 256, 0, stream>>>(src, dst, offsets, rank, srcs);

    const int agg_grid = (N_NODES * 64 + 255) / 256;
    const int mlp_grid = (N_NODES + 63) / 64;

    unsigned short* zin = zA;
    unsigned short* znext = zB;
    for (int l = 0; l < N_LAYERS; ++l) {
        agg_kernel<<<agg_grid, 256, 0, stream>>>(zin, offsets, srcs, bufh);
        if (l == N_LAYERS - 1) {
            mlp_fused<true><<<mlp_grid, 128, 0, stream>>>(
                bufh, wt + (size_t)l * DIM * DIM, bs1 + (size_t)l * DIM,
                wt + (size_t)(3 + l) * DIM * DIM, bs2 + (size_t)l * DIM, out, N_NODES);
        } else {
            mlp_fused<false><<<mlp_grid, 128, 0, stream>>>(
                bufh, wt + (size_t)l * DIM * DIM, bs1 + (size_t)l * DIM,
                wt + (size_t)(3 + l) * DIM * DIM, bs2 + (size_t)l * DIM, znext, N_NODES);
            unsigned short* tmp = zin; zin = znext; znext = tmp;
        }
    }
}